// Round 11
// baseline (4462.627 us; speedup 1.0000x reference)
//
#include <hip/hip_runtime.h>
#include <cstdint>
#include <cstddef>

#define B_   64
#define T_   512
#define E_   512
#define H_   1024
#define G4_  4096
#define KTOT 1536
#define NWG  256

typedef float f32x4 __attribute__((ext_vector_type(4)));
typedef int   i32x4 __attribute__((ext_vector_type(4)));

#define OFF_XE    ((size_t)0)
#define OFF_WC    (OFF_XE + (size_t)T_*B_*E_*2)     // 32 MB
#define OFF_BIAS  (OFF_WC + (size_t)G4_*KTOT*2)     // +12.6 MB
#define OFF_H0    (OFF_BIAS + (size_t)G4_*4)
#define OFF_FLAGS (OFF_H0 + (size_t)B_*H_*2)

__device__ __forceinline__ unsigned short f2b(float f) {
    unsigned u = __float_as_uint(f);
    return (unsigned short)((u + 0x7fffu + ((u >> 16) & 1u)) >> 16);  // RNE
}

// pack 8 f32 -> 8 bf16 (one MFMA A-frag) via v_cvt_pk_bf16_f32 (RNE)
__device__ __forceinline__ i32x4 cvt8(f32x4 lo, f32x4 hi) {
    unsigned p0, p1, p2, p3;
    asm("v_cvt_pk_bf16_f32 %0, %1, %2" : "=v"(p0) : "v"(lo[0]), "v"(lo[1]));
    asm("v_cvt_pk_bf16_f32 %0, %1, %2" : "=v"(p1) : "v"(lo[2]), "v"(lo[3]));
    asm("v_cvt_pk_bf16_f32 %0, %1, %2" : "=v"(p2) : "v"(hi[0]), "v"(hi[1]));
    asm("v_cvt_pk_bf16_f32 %0, %1, %2" : "=v"(p3) : "v"(hi[2]), "v"(hi[3]));
    i32x4 r = {(int)p0, (int)p1, (int)p2, (int)p3};
    return r;
}

// Permuted combined weights: permuted row p = s*64 + q*16 + hl  <->
// original gate row q*1024 + s*16 + hl (q: i,f,g,o; s: 16-hdim block).
__global__ void prep_w(const float* __restrict__ wih, const float* __restrict__ whh,
                       const float* __restrict__ bih, const float* __restrict__ bhh,
                       unsigned short* __restrict__ Wc, float* __restrict__ bp) {
    int p = blockIdx.x;
    int s = p >> 6, q = (p >> 4) & 3, hl = p & 15;
    int orig = q * H_ + s * 16 + hl;
    unsigned short* dst = Wc + (size_t)p * KTOT;
    const float* s1 = wih + (size_t)orig * E_;
    const float* s2 = whh + (size_t)orig * H_;
    int tx = threadIdx.x;
#pragma unroll
    for (int i = 0; i < 2; ++i) dst[tx + i*256] = f2b(s1[tx + i*256]);
#pragma unroll
    for (int i = 0; i < 4; ++i) dst[E_ + tx + i*256] = f2b(s2[tx + i*256]);
    if (tx == 0) bp[p] = bih[orig] + bhh[orig];
}

// xe[t][b][0:512] = bf16(emb[x[b][t]])
__global__ void prep_xe(const int* __restrict__ x, const float* __restrict__ emb,
                        unsigned short* __restrict__ xe) {
    int bid = blockIdx.x;
    int t = bid >> 6, b = bid & 63;
    int idx = x[b * T_ + t];
    const float* src = emb + (size_t)idx * E_;
    unsigned short* dst = xe + ((size_t)t * B_ + b) * E_;
    int tx = threadIdx.x;
    dst[tx] = f2b(src[tx]);
    dst[tx + 256] = f2b(src[tx + 256]);
}

__global__ void prep_h(const float* __restrict__ h0, unsigned short* __restrict__ hb) {
    int b = blockIdx.x;
#pragma unroll
    for (int i = 0; i < 4; ++i) {
        int j = threadIdx.x + i*256;
        hb[(size_t)b * H_ + j] = f2b(h0[(size_t)b * H_ + j]);
    }
}

// Persistent kernel, plain launch. 256 WGs = 4 INDEPENDENT groups of 64 WGs
// (g = blockIdx&3 owns batch rows [16g,16g+16); s = blockIdx>>2 -> 64 gate
// cols). 256 threads = 4 waves (ch = col half, kh = K half). Weights in
// AGPRs all T. h travels through out[] (agent bypass stores; fresh-address
// cached loads, L2-deduped). DE-DRAINED BARRIER: per-wave vmcnt(0) store-ack
// -> per-wave lane0 fetch_add (256 arrivals/group, 8 sublines); xe(t+1)
// prefetch issued after ack stays IN FLIGHT across the poll (release is a
// raw s_barrier, no compiler vmcnt(0) drain). Wave0 polls; LDS dead-flag.
__global__ __launch_bounds__(256, 1)
void lstm_pers(const unsigned short* __restrict__ xe,
               const unsigned short* __restrict__ Wc,
               const float* __restrict__ bp,
               const float* __restrict__ c0,
               const unsigned short* __restrict__ hb0,
               float* __restrict__ out,
               int* __restrict__ flags) {
    __shared__ float gpart[2][16][68];
    __shared__ int sh_dead;

    const int tid = threadIdx.x;
    const int wg  = blockIdx.x;
    const int g   = wg & 3;              // batch group: rows [16g, 16g+16)
    const int s   = wg >> 2;             // gate block: permuted cols [64s, 64s+64)
    const int w = tid >> 6, l = tid & 63;
    const int ch = w >> 1, kh = w & 1;
    const int lc = l & 15;               // lane col (B) / row (A)
    const int lk = (l >> 4) << 3;        // lane k-offset (elements)

    // ---- W fragments (AGPRs via "a" asm constraints): j<8 xe, j>=8 h ----
    i32x4 wreg0[24], wreg1[24];
    {
        const unsigned short* wrow0 = Wc + (size_t)((s << 6) + (ch << 5) + lc) * KTOT;
        const unsigned short* wrow1 = wrow0 + (size_t)16 * KTOT;
#pragma unroll
        for (int j = 0; j < 8; ++j) {
            int k = (kh << 8) + j * 32 + lk;
            wreg0[j] = *(const i32x4*)(wrow0 + k);
            wreg1[j] = *(const i32x4*)(wrow1 + k);
        }
#pragma unroll
        for (int j = 0; j < 16; ++j) {
            int k = 512 + (kh << 9) + j * 32 + lk;
            wreg0[8 + j] = *(const i32x4*)(wrow0 + k);
            wreg1[8 + j] = *(const i32x4*)(wrow1 + k);
        }
    }

    const int brow = (g << 4) + lc;      // global batch row this lane loads

    // ---- cell ownership: thread (b_c, hl_c); c stays in a register all T ----
    const int b_c = tid >> 4, hl_c = tid & 15;
    const int bglob = (g << 4) + b_c;
    const int hdim = (s << 4) + hl_c;
    float c = c0[(size_t)bglob * H_ + hdim];
    const float bi  = bp[(s << 6) + hl_c];
    const float bf_ = bp[(s << 6) + 16 + hl_c];
    const float bg  = bp[(s << 6) + 32 + hl_c];
    const float bo  = bp[(s << 6) + 48 + hl_c];

    int* subc = &flags[g << 10];         // 8 sub-counters, 128 B apart
    const int si = (wg >> 2) & 7;        // this WG's sub-counter

    if (tid == 0) sh_dead = 0;

    i32x4 a[24];
    {   // t=0 xe frags (later steps prefetch them inside the barrier window)
        const unsigned short* xp = xe + ((size_t)brow) * E_ + (kh << 8) + lk;
#pragma unroll
        for (int j = 0; j < 8; ++j) a[j] = *(const i32x4*)(xp + j * 32);
    }

    for (int t = 0; t < T_; ++t) {
        // ---- h frags: 16 per wave, d in [kh*512, kh*512+512) ----
        if (t == 0) {
            const unsigned short* hp = hb0 + (size_t)brow * H_ + (kh << 9) + lk;
#pragma unroll
            for (int j = 0; j < 16; ++j) a[8 + j] = *(const i32x4*)(hp + j * 32);
        } else {
            const float* hpf = out + ((size_t)brow * T_ + (t - 1)) * H_ + (kh << 9) + lk;
#pragma unroll
            for (int j = 0; j < 16; ++j) {
                f32x4 lo = *(const f32x4*)(hpf + j * 32);
                f32x4 hi = *(const f32x4*)(hpf + j * 32 + 4);
                a[8 + j] = cvt8(lo, hi);
            }
        }

        f32x4 acc0 = {0.f, 0.f, 0.f, 0.f};
        f32x4 acc1 = {0.f, 0.f, 0.f, 0.f};
        // xe MFMAs first (prefetched operands) run while h loads are in
        // flight. s_nop prefixes cover VALU->MFMA SrcA/SrcC hazards.
        asm volatile("s_nop 3\n\tv_mfma_f32_16x16x32_bf16 %0, %1, %2, %0"
                     : "+v"(acc0) : "v"(a[0]), "a"(wreg0[0]));
        asm volatile("s_nop 3\n\tv_mfma_f32_16x16x32_bf16 %0, %1, %2, %0"
                     : "+v"(acc1) : "v"(a[0]), "a"(wreg1[0]));
#pragma unroll
        for (int j = 1; j < 24; ++j) {
            asm volatile("s_nop 1\n\tv_mfma_f32_16x16x32_bf16 %0, %1, %2, %0"
                         : "+v"(acc0) : "v"(a[j]), "a"(wreg0[j]));
            asm volatile("s_nop 1\n\tv_mfma_f32_16x16x32_bf16 %0, %1, %2, %0"
                         : "+v"(acc1) : "v"(a[j]), "a"(wreg1[j]));
        }
        asm volatile("s_nop 7\n\ts_nop 7\n\ts_nop 7"
                     : "+v"(acc0), "+v"(acc1) :: "memory");  // MFMA -> read D
        {
            const int grow = (l >> 4) << 2;
            const int cb = (ch << 5) + lc;
#pragma unroll
            for (int j = 0; j < 4; ++j) {
                gpart[kh][grow + j][cb]      = acc0[j];
                gpart[kh][grow + j][cb + 16] = acc1[j];
            }
        }
        __syncthreads();

        // ---- LSTM cell (one (b,hdim) per thread) ----
        {
            float xi = gpart[0][b_c][hl_c]      + gpart[1][b_c][hl_c]      + bi;
            float xf = gpart[0][b_c][16 + hl_c] + gpart[1][b_c][16 + hl_c] + bf_;
            float xg = gpart[0][b_c][32 + hl_c] + gpart[1][b_c][32 + hl_c] + bg;
            float xo = gpart[0][b_c][48 + hl_c] + gpart[1][b_c][48 + hl_c] + bo;
            float iv = 1.f / (1.f + __expf(-xi));
            float fv = 1.f / (1.f + __expf(-xf));
            float eg = __expf(2.f * fminf(fmaxf(xg, -15.f), 15.f));
            float gv = (eg - 1.f) / (eg + 1.f);
            float ov = 1.f / (1.f + __expf(-xo));
            c = fv * c + iv * gv;
            float ec = __expf(2.f * fminf(fmaxf(c, -15.f), 15.f));
            float th = (ec - 1.f) / (ec + 1.f);
            float hv = ov * th;
            // bypass store -> coherent point; this IS the h broadcast
            __hip_atomic_store(&out[((size_t)bglob * T_ + t) * H_ + hdim], hv,
                               __ATOMIC_RELAXED, __HIP_MEMORY_SCOPE_AGENT);
        }

        if (t == T_ - 1) break;

        // ---- de-drained barrier ----
        __builtin_amdgcn_sched_barrier(0);
        asm volatile("s_waitcnt vmcnt(0)" ::: "memory");   // own h store acked
        __builtin_amdgcn_sched_barrier(0);
        {   // xe(t+1) prefetch: in flight across arrival+poll+release
            const unsigned short* xp = xe + ((size_t)(t + 1) * B_ + brow) * E_
                                          + (kh << 8) + lk;
#pragma unroll
            for (int j = 0; j < 8; ++j) a[j] = *(const i32x4*)(xp + j * 32);
        }
        if (l == 0)                                        // per-wave arrival
            __hip_atomic_fetch_add(&subc[si << 5], 1, __ATOMIC_RELAXED,
                                   __HIP_MEMORY_SCOPE_AGENT);
        if (w == 0) {                                      // wave0 polls 8 subs
            int dead = 0;
            const int tgt = (t + 1) << 5;                  // 32*(t+1), monotonic
            unsigned spin = 0;
            for (;;) {
                int v = (l < 8)
                    ? __hip_atomic_load(&subc[l << 5], __ATOMIC_RELAXED,
                                        __HIP_MEMORY_SCOPE_AGENT)
                    : tgt;
                if (__all(v >= tgt)) break;
                __builtin_amdgcn_s_sleep(1);
                if (++spin > (1u << 16)) { dead = 1; break; }  // escape, no hang
            }
            if (l == 0) sh_dead = dead;
        }
        asm volatile("s_waitcnt lgkmcnt(0)" ::: "memory"); // dead-flag visible
        __builtin_amdgcn_s_barrier();                      // raw release, no drain
        __builtin_amdgcn_sched_barrier(0);
        if (sh_dead) break;                                // uniform exit
        asm volatile("" ::: "memory");   // next-step loads can't hoist above
    }
}

extern "C" void kernel_launch(void* const* d_in, const int* in_sizes, int n_in,
                              void* d_out, int out_size, void* d_ws, size_t ws_size,
                              hipStream_t stream) {
    const int*   x   = (const int*)  d_in[0];
    const float* emb = (const float*)d_in[1];
    const float* wih = (const float*)d_in[2];
    const float* whh = (const float*)d_in[3];
    const float* bih = (const float*)d_in[4];
    const float* bhh = (const float*)d_in[5];
    const float* h0  = (const float*)d_in[6];
    const float* c0  = (const float*)d_in[7];
    float* out = (float*)d_out;
    char* ws = (char*)d_ws;

    unsigned short* xe  = (unsigned short*)(ws + OFF_XE);
    unsigned short* Wc  = (unsigned short*)(ws + OFF_WC);
    float*          bp  = (float*)(ws + OFF_BIAS);
    unsigned short* hb0 = (unsigned short*)(ws + OFF_H0);
    int*            flg = (int*)(ws + OFF_FLAGS);

    (void)hipMemsetAsync(flg, 0, 4096 * sizeof(int), stream);
    prep_w <<<dim3(G4_),   dim3(256), 0, stream>>>(wih, whh, bih, bhh, Wc, bp);
    prep_xe<<<dim3(B_*T_), dim3(256), 0, stream>>>(x, emb, xe);
    prep_h <<<dim3(B_),    dim3(256), 0, stream>>>(h0, hb0);

    lstm_pers<<<dim3(NWG), dim3(256), 0, stream>>>(xe, Wc, bp, c0, hb0, out, flg);
}

// Round 12
// 2218.878 us; speedup vs baseline: 2.0112x; 2.0112x over previous
//
#include <hip/hip_runtime.h>
#include <cstdint>
#include <cstddef>

#define B_   64
#define T_   512
#define E_   512
#define H_   1024
#define G4_  4096
#define KTOT 1536
#define NWG  256

typedef float f32x4 __attribute__((ext_vector_type(4)));
typedef int   i32x4 __attribute__((ext_vector_type(4)));

#define OFF_XE    ((size_t)0)
#define OFF_WC    (OFF_XE + (size_t)T_*B_*E_*2)     // 32 MB
#define OFF_BIAS  (OFF_WC + (size_t)G4_*KTOT*2)     // +12.6 MB
#define OFF_H0    (OFF_BIAS + (size_t)G4_*4)
#define OFF_FLAGS (OFF_H0 + (size_t)B_*H_*2)
#define OFF_HBT   (OFF_FLAGS + (size_t)16384)       // bf16 h history, 64 MB
#define WS_NEED_V2 (OFF_HBT + (size_t)T_*B_*H_*2)

__device__ __forceinline__ unsigned short f2b(float f) {
    unsigned u = __float_as_uint(f);
    return (unsigned short)((u + 0x7fffu + ((u >> 16) & 1u)) >> 16);  // RNE
}

// pack 8 f32 -> 8 bf16 via v_cvt_pk_bf16_f32 (RNE) — used by fallback kernel
__device__ __forceinline__ i32x4 cvt8(f32x4 lo, f32x4 hi) {
    unsigned p0, p1, p2, p3;
    asm("v_cvt_pk_bf16_f32 %0, %1, %2" : "=v"(p0) : "v"(lo[0]), "v"(lo[1]));
    asm("v_cvt_pk_bf16_f32 %0, %1, %2" : "=v"(p1) : "v"(lo[2]), "v"(lo[3]));
    asm("v_cvt_pk_bf16_f32 %0, %1, %2" : "=v"(p2) : "v"(hi[0]), "v"(hi[1]));
    asm("v_cvt_pk_bf16_f32 %0, %1, %2" : "=v"(p3) : "v"(hi[2]), "v"(hi[3]));
    i32x4 r = {(int)p0, (int)p1, (int)p2, (int)p3};
    return r;
}

// Permuted combined weights: permuted row p = s*64 + q*16 + hl  <->
// original gate row q*1024 + s*16 + hl (q: i,f,g,o; s: 16-hdim block).
__global__ void prep_w(const float* __restrict__ wih, const float* __restrict__ whh,
                       const float* __restrict__ bih, const float* __restrict__ bhh,
                       unsigned short* __restrict__ Wc, float* __restrict__ bp) {
    int p = blockIdx.x;
    int s = p >> 6, q = (p >> 4) & 3, hl = p & 15;
    int orig = q * H_ + s * 16 + hl;
    unsigned short* dst = Wc + (size_t)p * KTOT;
    const float* s1 = wih + (size_t)orig * E_;
    const float* s2 = whh + (size_t)orig * H_;
    int tx = threadIdx.x;
#pragma unroll
    for (int i = 0; i < 2; ++i) dst[tx + i*256] = f2b(s1[tx + i*256]);
#pragma unroll
    for (int i = 0; i < 4; ++i) dst[E_ + tx + i*256] = f2b(s2[tx + i*256]);
    if (tx == 0) bp[p] = bih[orig] + bhh[orig];
}

__global__ void prep_xe(const int* __restrict__ x, const float* __restrict__ emb,
                        unsigned short* __restrict__ xe) {
    int bid = blockIdx.x;
    int t = bid >> 6, b = bid & 63;
    int idx = x[b * T_ + t];
    const float* src = emb + (size_t)idx * E_;
    unsigned short* dst = xe + ((size_t)t * B_ + b) * E_;
    int tx = threadIdx.x;
    dst[tx] = f2b(src[tx]);
    dst[tx + 256] = f2b(src[tx + 256]);
}

__global__ void prep_h(const float* __restrict__ h0, unsigned short* __restrict__ hb) {
    int b = blockIdx.x;
#pragma unroll
    for (int i = 0; i < 4; ++i) {
        int j = threadIdx.x + i*256;
        hb[(size_t)b * H_ + j] = f2b(h0[(size_t)b * H_ + j]);
    }
}

// ===================== v2: bf16 fresh-address transport =====================
// 256 WGs = 4 groups of 64 (g = wg&3 owns rows [16g,16g+16); s = wg>>2 ->
// 64 gate cols). 4 waves (ch = col half, kh = K half). Weights in AGPRs.
// h(t) bypass-stored as bf16 into hbt[t] (fresh addresses for all T);
// consumers use PLAIN CACHED loads (first touch after release -> L2 miss ->
// MALL has it; L2 dedups the broadcast). out[] is written nontemporal AFTER
// the arrival add -> its ack is off the critical path. Busy poll, no sleep.
__global__ __launch_bounds__(256, 1)
void lstm_v2(const unsigned short* __restrict__ xe,
             const unsigned short* __restrict__ Wc,
             const float* __restrict__ bp,
             const float* __restrict__ c0,
             const unsigned short* __restrict__ hb0,
             unsigned short* __restrict__ hbt,
             float* __restrict__ out,
             int* __restrict__ flags) {
    __shared__ float gpart[2][16][68];

    const int tid = threadIdx.x;
    const int wg  = blockIdx.x;
    const int g   = wg & 3;
    const int s   = wg >> 2;
    const int w = tid >> 6, l = tid & 63;
    const int ch = w >> 1, kh = w & 1;
    const int lc = l & 15;
    const int lk = (l >> 4) << 3;

    i32x4 wreg0[24], wreg1[24];
    {
        const unsigned short* wrow0 = Wc + (size_t)((s << 6) + (ch << 5) + lc) * KTOT;
        const unsigned short* wrow1 = wrow0 + (size_t)16 * KTOT;
#pragma unroll
        for (int j = 0; j < 8; ++j) {
            int k = (kh << 8) + j * 32 + lk;
            wreg0[j] = *(const i32x4*)(wrow0 + k);
            wreg1[j] = *(const i32x4*)(wrow1 + k);
        }
#pragma unroll
        for (int j = 0; j < 16; ++j) {
            int k = 512 + (kh << 9) + j * 32 + lk;
            wreg0[8 + j] = *(const i32x4*)(wrow0 + k);
            wreg1[8 + j] = *(const i32x4*)(wrow1 + k);
        }
    }

    const int brow = (g << 4) + lc;

    const int b_c = tid >> 4, hl_c = tid & 15;
    const int bglob = (g << 4) + b_c;
    const int hdim = (s << 4) + hl_c;
    float c = c0[(size_t)bglob * H_ + hdim];
    const float bi  = bp[(s << 6) + hl_c];
    const float bf_ = bp[(s << 6) + 16 + hl_c];
    const float bg  = bp[(s << 6) + 32 + hl_c];
    const float bo  = bp[(s << 6) + 48 + hl_c];

    int* subc = &flags[g << 10];         // 8 sub-counters, 128 B apart
    const int si = (wg >> 2) & 7;

    i32x4 a[24];
    {   // t=0 xe frags (later steps prefetch inside the barrier window)
        const unsigned short* xp = xe + ((size_t)brow) * E_ + (kh << 8) + lk;
#pragma unroll
        for (int j = 0; j < 8; ++j) a[j] = *(const i32x4*)(xp + j * 32);
    }

    for (int t = 0; t < T_; ++t) {
        // ---- h frags: bf16, uniform layout (hb0 at t=0, hbt[t-1] after) ----
        {
            const unsigned short* hsrc =
                (t == 0 ? hb0 : hbt + (size_t)(t - 1) * (B_ * H_))
                + (size_t)brow * H_ + (kh << 9) + lk;
#pragma unroll
            for (int j = 0; j < 16; ++j) a[8 + j] = *(const i32x4*)(hsrc + j * 32);
        }

        f32x4 acc0 = {0.f, 0.f, 0.f, 0.f};
        f32x4 acc1 = {0.f, 0.f, 0.f, 0.f};
        // xe MFMAs first (prefetched regs) overlap the in-flight h loads.
        asm volatile("s_nop 3\n\tv_mfma_f32_16x16x32_bf16 %0, %1, %2, %0"
                     : "+v"(acc0) : "v"(a[0]), "a"(wreg0[0]));
        asm volatile("s_nop 3\n\tv_mfma_f32_16x16x32_bf16 %0, %1, %2, %0"
                     : "+v"(acc1) : "v"(a[0]), "a"(wreg1[0]));
#pragma unroll
        for (int j = 1; j < 24; ++j) {
            asm volatile("s_nop 1\n\tv_mfma_f32_16x16x32_bf16 %0, %1, %2, %0"
                         : "+v"(acc0) : "v"(a[j]), "a"(wreg0[j]));
            asm volatile("s_nop 1\n\tv_mfma_f32_16x16x32_bf16 %0, %1, %2, %0"
                         : "+v"(acc1) : "v"(a[j]), "a"(wreg1[j]));
        }
        asm volatile("s_nop 7\n\ts_nop 7\n\ts_nop 7"
                     : "+v"(acc0), "+v"(acc1) :: "memory");
        {
            const int grow = (l >> 4) << 2;
            const int cb = (ch << 5) + lc;
#pragma unroll
            for (int j = 0; j < 4; ++j) {
                gpart[kh][grow + j][cb]      = acc0[j];
                gpart[kh][grow + j][cb + 16] = acc1[j];
            }
        }
        __syncthreads();

        // ---- LSTM cell ----
        float hv;
        {
            float xi = gpart[0][b_c][hl_c]      + gpart[1][b_c][hl_c]      + bi;
            float xf = gpart[0][b_c][16 + hl_c] + gpart[1][b_c][16 + hl_c] + bf_;
            float xg = gpart[0][b_c][32 + hl_c] + gpart[1][b_c][32 + hl_c] + bg;
            float xo = gpart[0][b_c][48 + hl_c] + gpart[1][b_c][48 + hl_c] + bo;
            float iv = 1.f / (1.f + __expf(-xi));
            float fv = 1.f / (1.f + __expf(-xf));
            float eg = __expf(2.f * fminf(fmaxf(xg, -15.f), 15.f));
            float gv = (eg - 1.f) / (eg + 1.f);
            float ov = 1.f / (1.f + __expf(-xo));
            c = fv * c + iv * gv;
            float ec = __expf(2.f * fminf(fmaxf(c, -15.f), 15.f));
            float th = (ec - 1.f) / (ec + 1.f);
            hv = ov * th;
        }
        const size_t oidx = ((size_t)bglob * T_ + t) * H_ + hdim;

        if (t == T_ - 1) {
            __builtin_nontemporal_store(hv, &out[oidx]);
            break;
        }

        // bf16 h broadcast: bypass store to coherent point (MFMA-ready payload)
        {
            unsigned long long hdst = (unsigned long long)
                (hbt + (size_t)t * (B_ * H_) + (size_t)bglob * H_ + hdim);
            unsigned hval = (unsigned)f2b(hv);
            asm volatile("global_store_short %0, %1, off sc0 sc1"
                         :: "v"(hdst), "v"(hval) : "memory");
        }
        asm volatile("s_waitcnt vmcnt(0)" ::: "memory");   // h store acked
        __syncthreads();                                   // all waves acked
        if (tid == 0)
            __hip_atomic_fetch_add(&subc[si << 5], 1, __ATOMIC_RELAXED,
                                   __HIP_MEMORY_SCOPE_AGENT);
        // off-critical-path work floats across the poll:
        __builtin_nontemporal_store(hv, &out[oidx]);       // f32 output
        {                                                  // xe(t+1) prefetch
            const unsigned short* xp = xe + ((size_t)(t + 1) * B_ + brow) * E_
                                          + (kh << 8) + lk;
#pragma unroll
            for (int j = 0; j < 8; ++j) a[j] = *(const i32x4*)(xp + j * 32);
        }
        int dead = 0;
        if (w == 0) {                                      // busy poll, no sleep
            const int tgt = (t + 1) << 3;                  // 8*(t+1), monotonic
            unsigned spin = 0;
            for (;;) {
                int v = (l < 8)
                    ? __hip_atomic_load(&subc[l << 5], __ATOMIC_RELAXED,
                                        __HIP_MEMORY_SCOPE_AGENT)
                    : ((t + 1) << 3);
                if (__all(v >= tgt)) break;
                if (++spin > (1u << 17)) { dead = 1; break; }  // escape, no hang
            }
        }
        if (__syncthreads_or(dead)) break;                 // uniform release
        asm volatile("" ::: "memory");
    }
}

// ============== fallback: verbatim R10 (f32-through-out transport) ==============
__global__ __launch_bounds__(256, 1)
void lstm_pers(const unsigned short* __restrict__ xe,
               const unsigned short* __restrict__ Wc,
               const float* __restrict__ bp,
               const float* __restrict__ c0,
               const unsigned short* __restrict__ hb0,
               float* __restrict__ out,
               int* __restrict__ flags) {
    __shared__ float gpart[2][16][68];

    const int tid = threadIdx.x;
    const int wg  = blockIdx.x;
    const int g   = wg & 3;
    const int s   = wg >> 2;
    const int w = tid >> 6, l = tid & 63;
    const int ch = w >> 1, kh = w & 1;
    const int lc = l & 15;
    const int lk = (l >> 4) << 3;

    i32x4 wreg0[24], wreg1[24];
    {
        const unsigned short* wrow0 = Wc + (size_t)((s << 6) + (ch << 5) + lc) * KTOT;
        const unsigned short* wrow1 = wrow0 + (size_t)16 * KTOT;
#pragma unroll
        for (int j = 0; j < 8; ++j) {
            int k = (kh << 8) + j * 32 + lk;
            wreg0[j] = *(const i32x4*)(wrow0 + k);
            wreg1[j] = *(const i32x4*)(wrow1 + k);
        }
#pragma unroll
        for (int j = 0; j < 16; ++j) {
            int k = 512 + (kh << 9) + j * 32 + lk;
            wreg0[8 + j] = *(const i32x4*)(wrow0 + k);
            wreg1[8 + j] = *(const i32x4*)(wrow1 + k);
        }
    }

    const int brow = (g << 4) + lc;
    const int b_c = tid >> 4, hl_c = tid & 15;
    const int bglob = (g << 4) + b_c;
    const int hdim = (s << 4) + hl_c;
    float c = c0[(size_t)bglob * H_ + hdim];
    const float bi  = bp[(s << 6) + hl_c];
    const float bf_ = bp[(s << 6) + 16 + hl_c];
    const float bg  = bp[(s << 6) + 32 + hl_c];
    const float bo  = bp[(s << 6) + 48 + hl_c];

    int* subc = &flags[g << 10];
    const int si = (wg >> 2) & 7;

    i32x4 a[24];
    {
        const unsigned short* xp = xe + ((size_t)brow) * E_ + (kh << 8) + lk;
#pragma unroll
        for (int j = 0; j < 8; ++j) a[j] = *(const i32x4*)(xp + j * 32);
    }

    for (int t = 0; t < T_; ++t) {
        if (t == 0) {
            const unsigned short* hp = hb0 + (size_t)brow * H_ + (kh << 9) + lk;
#pragma unroll
            for (int j = 0; j < 16; ++j) a[8 + j] = *(const i32x4*)(hp + j * 32);
        } else {
            const float* hpf = out + ((size_t)brow * T_ + (t - 1)) * H_ + (kh << 9) + lk;
#pragma unroll
            for (int j = 0; j < 16; ++j) {
                f32x4 lo = *(const f32x4*)(hpf + j * 32);
                f32x4 hi = *(const f32x4*)(hpf + j * 32 + 4);
                a[8 + j] = cvt8(lo, hi);
            }
        }

        f32x4 acc0 = {0.f, 0.f, 0.f, 0.f};
        f32x4 acc1 = {0.f, 0.f, 0.f, 0.f};
        asm volatile("s_nop 3\n\tv_mfma_f32_16x16x32_bf16 %0, %1, %2, %0"
                     : "+v"(acc0) : "v"(a[0]), "a"(wreg0[0]));
        asm volatile("s_nop 3\n\tv_mfma_f32_16x16x32_bf16 %0, %1, %2, %0"
                     : "+v"(acc1) : "v"(a[0]), "a"(wreg1[0]));
#pragma unroll
        for (int j = 1; j < 24; ++j) {
            asm volatile("s_nop 1\n\tv_mfma_f32_16x16x32_bf16 %0, %1, %2, %0"
                         : "+v"(acc0) : "v"(a[j]), "a"(wreg0[j]));
            asm volatile("s_nop 1\n\tv_mfma_f32_16x16x32_bf16 %0, %1, %2, %0"
                         : "+v"(acc1) : "v"(a[j]), "a"(wreg1[j]));
        }
        asm volatile("s_nop 7\n\ts_nop 7\n\ts_nop 7"
                     : "+v"(acc0), "+v"(acc1) :: "memory");
        {
            const int grow = (l >> 4) << 2;
            const int cb = (ch << 5) + lc;
#pragma unroll
            for (int j = 0; j < 4; ++j) {
                gpart[kh][grow + j][cb]      = acc0[j];
                gpart[kh][grow + j][cb + 16] = acc1[j];
            }
        }
        __syncthreads();

        {
            float xi = gpart[0][b_c][hl_c]      + gpart[1][b_c][hl_c]      + bi;
            float xf = gpart[0][b_c][16 + hl_c] + gpart[1][b_c][16 + hl_c] + bf_;
            float xg = gpart[0][b_c][32 + hl_c] + gpart[1][b_c][32 + hl_c] + bg;
            float xo = gpart[0][b_c][48 + hl_c] + gpart[1][b_c][48 + hl_c] + bo;
            float iv = 1.f / (1.f + __expf(-xi));
            float fv = 1.f / (1.f + __expf(-xf));
            float eg = __expf(2.f * fminf(fmaxf(xg, -15.f), 15.f));
            float gv = (eg - 1.f) / (eg + 1.f);
            float ov = 1.f / (1.f + __expf(-xo));
            c = fv * c + iv * gv;
            float ec = __expf(2.f * fminf(fmaxf(c, -15.f), 15.f));
            float th = (ec - 1.f) / (ec + 1.f);
            float hv = ov * th;
            __hip_atomic_store(&out[((size_t)bglob * T_ + t) * H_ + hdim], hv,
                               __ATOMIC_RELAXED, __HIP_MEMORY_SCOPE_AGENT);
        }

        if (t == T_ - 1) break;

        {
            const unsigned short* xp = xe + ((size_t)(t + 1) * B_ + brow) * E_
                                          + (kh << 8) + lk;
#pragma unroll
            for (int j = 0; j < 8; ++j) a[j] = *(const i32x4*)(xp + j * 32);
        }

        asm volatile("s_waitcnt vmcnt(0)" ::: "memory");
        __syncthreads();
        int dead = 0;
        if (tid == 0)
            __hip_atomic_fetch_add(&subc[si << 5], 1, __ATOMIC_RELAXED,
                                   __HIP_MEMORY_SCOPE_AGENT);
        if (w == 0) {
            const int tgt = (t + 1) << 3;
            unsigned spin = 0;
            for (;;) {
                int v = (l < 8)
                    ? __hip_atomic_load(&subc[l << 5], __ATOMIC_RELAXED,
                                        __HIP_MEMORY_SCOPE_AGENT)
                    : tgt;
                if (__all(v >= tgt)) break;
                __builtin_amdgcn_s_sleep(1);
                if (++spin > (1u << 18)) { dead = 1; break; }
            }
        }
        if (__syncthreads_or(dead)) break;
        asm volatile("" ::: "memory");
    }
}

extern "C" void kernel_launch(void* const* d_in, const int* in_sizes, int n_in,
                              void* d_out, int out_size, void* d_ws, size_t ws_size,
                              hipStream_t stream) {
    const int*   x   = (const int*)  d_in[0];
    const float* emb = (const float*)d_in[1];
    const float* wih = (const float*)d_in[2];
    const float* whh = (const float*)d_in[3];
    const float* bih = (const float*)d_in[4];
    const float* bhh = (const float*)d_in[5];
    const float* h0  = (const float*)d_in[6];
    const float* c0  = (const float*)d_in[7];
    float* out = (float*)d_out;
    char* ws = (char*)d_ws;

    unsigned short* xe  = (unsigned short*)(ws + OFF_XE);
    unsigned short* Wc  = (unsigned short*)(ws + OFF_WC);
    float*          bp  = (float*)(ws + OFF_BIAS);
    unsigned short* hb0 = (unsigned short*)(ws + OFF_H0);
    int*            flg = (int*)(ws + OFF_FLAGS);
    unsigned short* hbt = (unsigned short*)(ws + OFF_HBT);

    (void)hipMemsetAsync(flg, 0, 4096 * sizeof(int), stream);
    prep_w <<<dim3(G4_),   dim3(256), 0, stream>>>(wih, whh, bih, bhh, Wc, bp);
    prep_xe<<<dim3(B_*T_), dim3(256), 0, stream>>>(x, emb, xe);
    prep_h <<<dim3(B_),    dim3(256), 0, stream>>>(h0, hb0);

    if (ws_size >= WS_NEED_V2) {
        lstm_v2<<<dim3(NWG), dim3(256), 0, stream>>>(xe, Wc, bp, c0, hb0, hbt,
                                                     out, flg);
    } else {
        lstm_pers<<<dim3(NWG), dim3(256), 0, stream>>>(xe, Wc, bp, c0, hb0,
                                                       out, flg);
    }
}